// Round 4
// baseline (121.983 us; speedup 1.0000x reference)
//
#include <hip/hip_runtime.h>
#include <hip/hip_bf16.h>

typedef __attribute__((ext_vector_type(8))) __bf16 bf16x8;
typedef __attribute__((ext_vector_type(4))) float f32x4;
typedef unsigned short u16;

#define CIN   62
#define HW    224
#define NPIX  49

__device__ __forceinline__ u16 f2b(float f) {
    union { __hip_bfloat16 h; u16 u; } cv;
    cv.h = __float2bfloat16(f);
    return cv.u;
}

// LDS 64x64 bf16 tiles, row stride 64 elems (128B), XOR swizzle on 8-elem (16B) blocks
__device__ __forceinline__ bf16x8 ld8(const u16* buf, int row, int ecol) {
    int idx = (row << 6) + (ecol ^ ((row & 7) << 3));
    return *reinterpret_cast<const bf16x8*>(buf + idx);
}
__device__ __forceinline__ void st1(u16* buf, int row, int ecol, u16 v) {
    buf[(row << 6) + (ecol ^ ((row & 7) << 3))] = v;
}
__device__ __forceinline__ void st4(u16* buf, int row, int ecol, u16 a, u16 b, u16 c, u16 d) {
    int idx = (row << 6) + (ecol ^ ((row & 7) << 3));
    *reinterpret_cast<ushort4*>(buf + idx) = make_ushort4(a, b, c, d);
}

// wb rows 0..63   = G  = Wq^T Wk / 8   (S = X^T G X)
// wb rows 64..127 = Wf = Wp @ Wv       (Y = (Wf X) P^T)
__global__ void prep_weights(const float* __restrict__ wqkv, const float* __restrict__ wp,
                             u16* __restrict__ wb) {
    int t = blockIdx.x * 256 + threadIdx.x;   // 0 .. 128*64-1
    if (t >= 128 * 64) return;
    int o = t >> 6;
    int c = t & 63;
    float s = 0.0f;
    if (o < 64) {
        for (int m = 0; m < 64; ++m)
            s += wqkv[m * 64 + o] * wqkv[(64 + m) * 64 + c];
        s *= 0.125f;
    } else {
        int of = o - 64;
        if (of < CIN)
            for (int m = 0; m < 64; ++m)
                s += wp[of * 64 + m] * wqkv[(128 + m) * 64 + c];
    }
    wb[t] = f2b(s);
}

__global__ __launch_bounds__(256, 8) void win_attn(
    const float* __restrict__ x, const u16* __restrict__ wb,
    const float* __restrict__ bproj, float* __restrict__ out)
{
    __shared__ __align__(16) u16 t1[64 * 64];  // T[j][g]  -> later P[i][j]
    __shared__ __align__(16) u16 t2[64 * 64];  // F[co][j]

    const int tid  = threadIdx.x;
    const int lane = tid & 63;
    const int wid  = tid >> 6;
    const int lr   = lane & 15;
    const int lg   = lane >> 4;

    // XCD swizzle: each XCD gets one batch image (1024 consecutive windows)
    const int win = ((blockIdx.x & 7) << 10) | (blockIdx.x >> 3);
    const int b   = win >> 10;
    const int rem = win & 1023;
    const int hn  = rem >> 5;
    const int wn  = rem & 31;
    const int h0  = hn * 7, w0 = wn * 7;

    // this lane's pixel (B-frag col for GEMM1 / A-frag row for GEMM2)
    const int p     = wid * 16 + lr;
    const bool valid = p < NPIX;
    const int dh = p / 7, dw = p - dh * 7;
    const int h = h0 + dh, w = w0 + dw;
    const float cx = -1.0f + (2.0f / 223.0f) * (float)w;
    const float cy = -1.0f + (2.0f / 223.0f) * (float)h;
    const float* xp = x + (size_t)b * CIN * HW * HW + (size_t)h * HW + w;

    // ---- load X fragment straight into registers: channels ks*32 + lg*8 + e
    union { bf16x8 v; u16 u[8]; } xa[2];
#pragma unroll
    for (int ks = 0; ks < 2; ++ks)
#pragma unroll
        for (int e = 0; e < 8; ++e) {
            int c = ks * 32 + lg * 8 + e;
            float v = 0.0f;
            if (valid)
                v = (c < CIN) ? xp[(size_t)c * HW * HW] : ((c == 62) ? cx : cy);
            xa[ks].u[e] = f2b(v);
        }

    const f32x4 fz = {0.f, 0.f, 0.f, 0.f};

    // ---- GEMM1a: T(64 x this wave's 16 px) = G @ X   (M-tiles 0..3)
    {
        f32x4 acc1[4];
#pragma unroll
        for (int m = 0; m < 4; ++m) acc1[m] = fz;
#pragma unroll
        for (int ks = 0; ks < 2; ++ks)
#pragma unroll
            for (int m = 0; m < 4; ++m) {
                bf16x8 a = *reinterpret_cast<const bf16x8*>(wb + (m * 16 + lr) * 64 + ks * 32 + lg * 8);
                acc1[m] = __builtin_amdgcn_mfma_f32_16x16x32_bf16(a, xa[ks].v, acc1[m], 0, 0, 0);
            }
        // scatter T -> t1[j][g] (rows j = wave-private pixels)
#pragma unroll
        for (int m = 0; m < 4; ++m)
            st4(t1, p, m * 16 + lg * 4, f2b(acc1[m][0]), f2b(acc1[m][1]),
                                        f2b(acc1[m][2]), f2b(acc1[m][3]));
    }

    // ---- GEMM1b: F(64 x 16 px) = Wf @ X   (M-tiles 4..7)
    {
        f32x4 acc1[4];
#pragma unroll
        for (int m = 0; m < 4; ++m) acc1[m] = fz;
#pragma unroll
        for (int ks = 0; ks < 2; ++ks)
#pragma unroll
            for (int m = 0; m < 4; ++m) {
                bf16x8 a = *reinterpret_cast<const bf16x8*>(wb + ((m + 4) * 16 + lr) * 64 + ks * 32 + lg * 8);
                acc1[m] = __builtin_amdgcn_mfma_f32_16x16x32_bf16(a, xa[ks].v, acc1[m], 0, 0, 0);
            }
        // scatter F -> t2[co][j] (cols j = wave-private pixels)
#pragma unroll
        for (int m = 0; m < 4; ++m)
#pragma unroll
            for (int r = 0; r < 4; ++r)
                st1(t2, m * 16 + lg * 4 + r, p, f2b(acc1[m][r]));
    }
    __syncthreads();

    // ---- GEMM2: S[i][j] = sum_g X^T[i][g] T[j][g] ; A = xa (regs!), B = t1
    f32x4 s4[4];
#pragma unroll
    for (int n = 0; n < 4; ++n) s4[n] = fz;
#pragma unroll
    for (int ks = 0; ks < 2; ++ks)
#pragma unroll
        for (int n = 0; n < 4; ++n) {
            bf16x8 bt = ld8(t1, n * 16 + lr, ks * 32 + lg * 8);
            s4[n] = __builtin_amdgcn_mfma_f32_16x16x32_bf16(xa[ks].v, bt, s4[n], 0, 0, 0);
        }
    __syncthreads();   // all T-reads of t1 done; t1 can be recycled for P

    // ---- register softmax; write P rows (wave-private) into t1
#pragma unroll
    for (int r = 0; r < 4; ++r) {
        const int i = wid * 16 + lg * 4 + r;
        float v[4], mx = -1e30f;
#pragma unroll
        for (int n = 0; n < 4; ++n) {
            v[n] = s4[n][r];
            int j = n * 16 + lr;
            mx = fmaxf(mx, (j < NPIX) ? v[n] : -1e30f);
        }
        mx = fmaxf(mx, __shfl_xor(mx, 1));
        mx = fmaxf(mx, __shfl_xor(mx, 2));
        mx = fmaxf(mx, __shfl_xor(mx, 4));
        mx = fmaxf(mx, __shfl_xor(mx, 8));
        float e[4], sm = 0.f;
#pragma unroll
        for (int n = 0; n < 4; ++n) {
            int j = n * 16 + lr;
            e[n] = (j < NPIX) ? __expf(v[n] - mx) : 0.f;
            sm += e[n];
        }
        sm += __shfl_xor(sm, 1);
        sm += __shfl_xor(sm, 2);
        sm += __shfl_xor(sm, 4);
        sm += __shfl_xor(sm, 8);
        float sinv = 1.0f / sm;
#pragma unroll
        for (int n = 0; n < 4; ++n)
            st1(t1, i, n * 16 + lr, f2b(e[n] * sinv));
    }
    __syncthreads();

    // ---- GEMM3: Y[co][p] = sum_j F[co][j] P[p][j] ; A = t2, B = t1
    f32x4 y4[4];
#pragma unroll
    for (int n = 0; n < 4; ++n) y4[n] = fz;
#pragma unroll
    for (int ks = 0; ks < 2; ++ks) {
        bf16x8 af = ld8(t2, wid * 16 + lr, ks * 32 + lg * 8);
#pragma unroll
        for (int n = 0; n < 4; ++n) {
            bf16x8 bp = ld8(t1, n * 16 + lr, ks * 32 + lg * 8);
            y4[n] = __builtin_amdgcn_mfma_f32_16x16x32_bf16(af, bp, y4[n], 0, 0, 0);
        }
    }

    const int cb = wid * 16 + lg * 4;
    float bias[4];
#pragma unroll
    for (int r = 0; r < 4; ++r) bias[r] = (cb + r < CIN) ? bproj[cb + r] : 0.f;
#pragma unroll
    for (int n = 0; n < 4; ++n) {
        int po = n * 16 + lr;
        if (po < NPIX) {
            int dho = po / 7, dwo = po - dho * 7;
            int ho = h0 + dho, wo = w0 + dwo;
#pragma unroll
            for (int r = 0; r < 4; ++r) {
                int co = cb + r;
                if (co < CIN)
                    out[((b * CIN + co) * HW + ho) * HW + wo] = y4[n][r] + bias[r];
            }
        }
    }
}

extern "C" void kernel_launch(void* const* d_in, const int* in_sizes, int n_in,
                              void* d_out, int out_size, void* d_ws, size_t ws_size,
                              hipStream_t stream) {
    const float* x    = (const float*)d_in[0];
    const float* wqkv = (const float*)d_in[1];
    const float* wp   = (const float*)d_in[2];
    const float* bp   = (const float*)d_in[3];
    float* out = (float*)d_out;

    u16* wb = (u16*)d_ws;   // 128*64 bf16: [G = Wq^T Wk /8 ; Wf = Wp Wv]

    prep_weights<<<32, 256, 0, stream>>>(wqkv, wp, wb);
    win_attn<<<8192, 256, 0, stream>>>(x, wb, bp, out);
}